// Round 14
// baseline (133.643 us; speedup 1.0000x reference)
//
#include <hip/hip_runtime.h>
#include <hip/hip_bf16.h>
#include <stdint.h>

typedef __attribute__((ext_vector_type(4))) float f32x4;
typedef __attribute__((ext_vector_type(16))) float f32x16;
typedef __bf16 bf16x8v __attribute__((ext_vector_type(8)));
typedef __attribute__((ext_vector_type(4))) unsigned int u32x4;
typedef __attribute__((ext_vector_type(2))) unsigned int u32x2;

constexpr int NB = 2;
constexpr int NS = 2048;
constexpr int ND = 1024;
constexpr int NH = 16;
constexpr int NDK = 64;

__device__ __forceinline__ void gload16(const void* g, void* l) {
    __builtin_amdgcn_global_load_lds(
        (const __attribute__((address_space(1))) unsigned int*)g,
        (__attribute__((address_space(3))) unsigned int*)l, 16, 0, 0);
}

__device__ __forceinline__ unsigned pack_bf16x2(float lo, float hi) {
    unsigned short a = __builtin_bit_cast(unsigned short, (__bf16)lo);
    unsigned short b = __builtin_bit_cast(unsigned short, (__bf16)hi);
    return (unsigned)a | ((unsigned)b << 16);
}

// cross-half exchange: returns partner half's value of v (lane c <-> lane c+32)
__device__ __forceinline__ float xhalf(float v, int h) {
    const unsigned u = __builtin_bit_cast(unsigned, v);
    const u32x2 r = __builtin_amdgcn_permlane32_swap(u, u, false, false);
    return __builtin_bit_cast(float, h ? r[0] : r[1]);
}

// ---------------- prep: fp32->bf16 convert (x + 4 weights) + RoPE tables ----------------
__global__ void __launch_bounds__(256)
prep_kernel(const float* __restrict__ x, const float* __restrict__ wq,
            const float* __restrict__ wk, const float* __restrict__ wv,
            const float* __restrict__ wo, const int* __restrict__ pos,
            __bf16* __restrict__ xb, __bf16* __restrict__ wqb,
            __bf16* __restrict__ wkb, __bf16* __restrict__ wvb,
            __bf16* __restrict__ wob,
            float* __restrict__ cos_t, float* __restrict__ sin_t)
{
    int b = blockIdx.x;
    if (b >= 4096) {  // RoPE cos/sin tables [s][p], p=0..31
        const int idx = (b - 4096) * 256 + threadIdx.x;  // 65536 = 2048*32
        const int s = idx >> 5, p = idx & 31;
        const float freq = __expf((float)p * (-0.28782313662425572f));  // ln(1e4)/32
        const float ang = (float)pos[s] * freq;
        float sn, cs;
        sincosf(ang, &sn, &cs);
        cos_t[idx] = cs;
        sin_t[idx] = sn;
        return;
    }
    const float* s; __bf16* d;
    if (b < 2048)      { s = x;  d = xb;            }
    else if (b < 2560) { s = wq; d = wqb; b -= 2048; }
    else if (b < 3072) { s = wk; d = wkb; b -= 2560; }
    else if (b < 3584) { s = wv; d = wvb; b -= 3072; }
    else               { s = wo; d = wob; b -= 3584; }
    const size_t i = ((size_t)b * 256 + threadIdx.x) * 8;
    const f32x4 v0 = *(const f32x4*)(s + i);
    const f32x4 v1 = *(const f32x4*)(s + i + 4);
    bf16x8v o;
#pragma unroll
    for (int j = 0; j < 4; ++j) { o[j] = (__bf16)v0[j]; o[4+j] = (__bf16)v1[j]; }
    *(bf16x8v*)(d + i) = o;
}

// ---- shared GEMM epilogue piece (RoPE-from-table or V^T store), no calls ----
__device__ __forceinline__ void epi_one(
    f32x4 a, int fm, int fn, int bm, int wm, int g, int c, int mode, int h_out,
    const float* __restrict__ cos_t, const float* __restrict__ sin_t,
    __bf16* __restrict__ qw, __bf16* __restrict__ kw, __bf16* __restrict__ vtw)
{
    const int m0 = bm * 128 + wm * 64 + fm * 16 + g * 4;
    const int bI = m0 >> 11, s0 = m0 & (NS - 1);
    const int d = fn * 16 + c;
    float v0 = a[0], v1 = a[1], v2 = a[2], v3 = a[3];
    if (mode < 2) {
        const int p = d >> 1;
        const bool odd = (d & 1);
        const float sc = (mode == 0) ? 0.18033688011112042f : 1.0f;  // 0.125*log2(e)
#define ROPE1(V, I)                                                        \
        {                                                                  \
            const float cs = cos_t[(s0 + (I)) * 32 + p];                   \
            const float sn = sin_t[(s0 + (I)) * 32 + p];                   \
            const float oth = __shfl_xor(V, 1, 64);                       \
            V = (odd ? (oth * sn + V * cs) : (V * cs - oth * sn)) * sc;    \
        }
        ROPE1(v0, 0) ROPE1(v1, 1) ROPE1(v2, 2) ROPE1(v3, 3)
#undef ROPE1
        __bf16* dq = (mode == 0) ? qw : kw;
        __bf16* b = dq + (((size_t)bI * NH + h_out) * NS + s0) * NDK + d;
        b[0] = (__bf16)v0; b[NDK] = (__bf16)v1;
        b[2 * NDK] = (__bf16)v2; b[3 * NDK] = (__bf16)v3;
    } else {
        ushort4 pk;
        pk.x = __builtin_bit_cast(unsigned short, (__bf16)v0);
        pk.y = __builtin_bit_cast(unsigned short, (__bf16)v1);
        pk.z = __builtin_bit_cast(unsigned short, (__bf16)v2);
        pk.w = __builtin_bit_cast(unsigned short, (__bf16)v3);
        *(ushort4*)&vtw[(((size_t)bI * NH + h_out) * NDK + d) * NS + s0] = pk;
    }
}

// ---------------- fused QKV projection GEMM (m97 structure, 3 blocks/CU) ----------------
__global__ void __launch_bounds__(256, 3)
qkv_kernel(const __bf16* __restrict__ xb,
           const __bf16* __restrict__ wqb, const __bf16* __restrict__ wkb,
           const __bf16* __restrict__ wvb,
           const float* __restrict__ cos_t, const float* __restrict__ sin_t,
           __bf16* __restrict__ qw, __bf16* __restrict__ kw,
           __bf16* __restrict__ vtw)
{
    __shared__ __align__(16) __bf16 a_lds[128 * 32];
    __shared__ __align__(16) __bf16 b_lds[128 * 32];

    const int t = threadIdx.x, w = t >> 6, lane = t & 63;
    const int g = lane >> 4, c = lane & 15;
    const int bm = blockIdx.x, bn = blockIdx.y;
    const int mode = bn >> 3, nblk = bn & 7;
    const __bf16* wsel = (mode == 0) ? wqb : (mode == 1) ? wkb : wvb;
    const int wm = w >> 1, wn = w & 1;

    f32x4 acc00 = {}, acc01 = {}, acc02 = {}, acc03 = {};
    f32x4 acc10 = {}, acc11 = {}, acc12 = {}, acc13 = {};
    f32x4 acc20 = {}, acc21 = {}, acc22 = {}, acc23 = {};
    f32x4 acc30 = {}, acc31 = {}, acc32 = {}, acc33 = {};

    const int sl = (g ^ (c & 3)) * 8;
    const __bf16* arow = &a_lds[(wm * 64 + c) * 32 + sl];
    const __bf16* brow = &b_lds[(wn * 64 + c) * 32 + sl];

    for (int kt = 0; kt < 32; ++kt) {
        __syncthreads();
#pragma unroll
        for (int j = 0; j < 2; ++j) {
            const int G = (w * 2 + j) * 64 + lane;
            const int r = G >> 2, cb = (G & 3) ^ (r & 3);
            gload16(xb   + (size_t)(bm   * 128 + r) * ND + kt * 32 + cb * 8,
                    &a_lds[(w * 2 + j) * 512]);
            gload16(wsel + (size_t)(nblk * 128 + r) * ND + kt * 32 + cb * 8,
                    &b_lds[(w * 2 + j) * 512]);
        }
        __syncthreads();
        const bf16x8v af0 = *(const bf16x8v*)(arow);
        const bf16x8v af1 = *(const bf16x8v*)(arow + 512);
        const bf16x8v af2 = *(const bf16x8v*)(arow + 1024);
        const bf16x8v af3 = *(const bf16x8v*)(arow + 1536);
        const bf16x8v bf0 = *(const bf16x8v*)(brow);
        const bf16x8v bf1 = *(const bf16x8v*)(brow + 512);
        const bf16x8v bf2 = *(const bf16x8v*)(brow + 1024);
        const bf16x8v bf3 = *(const bf16x8v*)(brow + 1536);
#define MM(FM, FN) acc##FM##FN = __builtin_amdgcn_mfma_f32_16x16x32_bf16( \
        af##FM, bf##FN, acc##FM##FN, 0, 0, 0);
        MM(0,0) MM(0,1) MM(0,2) MM(0,3)
        MM(1,0) MM(1,1) MM(1,2) MM(1,3)
        MM(2,0) MM(2,1) MM(2,2) MM(2,3)
        MM(3,0) MM(3,1) MM(3,2) MM(3,3)
#undef MM
    }

    const int h_out = nblk * 2 + wn;
#define EP(FM, FN) epi_one(acc##FM##FN, FM, FN, bm, wm, g, c, mode, h_out, \
                           cos_t, sin_t, qw, kw, vtw);
    EP(0,0) EP(0,1) EP(0,2) EP(0,3)
    EP(1,0) EP(1,1) EP(1,2) EP(1,3)
    EP(2,0) EP(2,1) EP(2,2) EP(2,3)
    EP(3,0) EP(3,1) EP(3,2) EP(3,3)
#undef EP
}

// ---------------- flash attention v12: NO KV LDS, no main-loop barriers ----------------
// K/V tiles have only 4-8x reuse and L1/L2-fit (Common-mistake #7: staging
// cache-fitting data is overhead): each wave loads its MFMA fragments DIRECTLY
// from global (8 K + 8 V global_load_dwordx4 per tile; each 128B line touched
// once after L1 fill). No staging, no bank conflicts, no barriers -> waves slip
// phase freely and overlap across blocks. 1024 blocks x 4 waves: wave (qs,half)
// owns 32 q-rows of a 64-row tile (qt32 pair-balanced) and half the K-tiles;
// pair-merge via small LDS at the end. V loads after softmax to cap VGPR.
// q,k: [b*16+h][s][64] bf16 (q pre-scaled by 0.125*log2e); vt: [b*16+h][d][s].
__global__ void __launch_bounds__(256)
__attribute__((amdgpu_waves_per_eu(4, 4)))
attn_kernel(const __bf16* __restrict__ q, const __bf16* __restrict__ k,
            const __bf16* __restrict__ vt, __bf16* __restrict__ o)
{
    __shared__ __align__(16) float smem_f[4352];  // 2 pairs x 2176 floats (17.4 KB)

    const int t = threadIdx.x, w = t >> 6, lane = t & 63;
    const int c = lane & 31, h = lane >> 5;
    const int qs = w >> 1, half = w & 1;
    const int bid = blockIdx.x;
    const int idx = bid >> 5;                          // 0..31
    const int qt32 = (idx < 16) ? (31 - idx) : (idx - 16);  // pairs sum to 31
    const int bh = bid & 31;                           // B*H = 32
    const size_t base = (size_t)bh * NS * NDK;
    const int q0 = qt32 * 64 + qs * 32;
    const int kd_w = qt32;                             // diagonal tile index
    const int NT = qt32 + 1;                           // tiles for this q-tile
    const int NH0 = (NT + 1) >> 1;                     // half0 tile count
    const int Tof = half * NH0;
    const int nIter = half ? (NT - NH0) : NH0;

    // Q B-frags: lane (c,h) holds Q[q0+c][16ds+8h+j]
    bf16x8v qf0, qf1, qf2, qf3;
    {
        const __bf16* qp = q + base + (size_t)(q0 + c) * NDK + h * 8;
        qf0 = *(const bf16x8v*)(qp);
        qf1 = *(const bf16x8v*)(qp + 16);
        qf2 = *(const bf16x8v*)(qp + 32);
        qf3 = *(const bf16x8v*)(qp + 48);
    }

    // direct per-lane fragment addressing (content identical to old LDS reads):
    // K frag(ds,lo): K[T*64 + c][(2ds+h)*8 ..]; V frag(S,lo): V^T[c][T*64+(2S+h)*8]
    const __bf16* kb_lo = k  + base + (size_t)c * NDK + h * 8;
    const __bf16* kb_hi = kb_lo + 32 * NDK;
    const __bf16* vb_lo = vt + base + (size_t)c * NS + h * 8;
    const __bf16* vb_hi = vb_lo + (size_t)32 * NS;

    float mrow = -3e38f, lrow = 0.f;
    f32x16 oa0 = {}, oa1 = {};

#define MX3(a, b, cc) fmaxf(fmaxf((a), (b)), (cc))
#define PV_STEP(ST, T, VL, VH)  {                                             \
    const unsigned w0_ = pack_bf16x2(ST[8*(T)+0], ST[8*(T)+1]);               \
    const unsigned w1_ = pack_bf16x2(ST[8*(T)+2], ST[8*(T)+3]);               \
    const unsigned w2_ = pack_bf16x2(ST[8*(T)+4], ST[8*(T)+5]);               \
    const unsigned w3_ = pack_bf16x2(ST[8*(T)+6], ST[8*(T)+7]);               \
    const u32x2 r02 = __builtin_amdgcn_permlane32_swap(w0_, w2_, false, false); \
    const u32x2 r13 = __builtin_amdgcn_permlane32_swap(w1_, w3_, false, false); \
    const u32x4 pu = { r02[0], r13[0], r02[1], r13[1] };                      \
    const bf16x8v pf = __builtin_bit_cast(bf16x8v, pu);                       \
    oa0 = __builtin_amdgcn_mfma_f32_32x32x16_bf16(VL, pf, oa0, 0, 0, 0);      \
    oa1 = __builtin_amdgcn_mfma_f32_32x32x16_bf16(VH, pf, oa1, 0, 0, 0); }

    for (int i = 0; i < nIter; ++i) {
        const int T = Tof + i;
        const size_t ko = (size_t)T * 4096;   // 64 rows * 64 cols
        const int vo = T * 64;

        // K fragments (direct global; stride-128B per lane, L1-resident tile)
        const bf16x8v k0l = *(const bf16x8v*)(kb_lo + ko);
        const bf16x8v k0h = *(const bf16x8v*)(kb_hi + ko);
        const bf16x8v k1l = *(const bf16x8v*)(kb_lo + ko + 16);
        const bf16x8v k1h = *(const bf16x8v*)(kb_hi + ko + 16);
        const bf16x8v k2l = *(const bf16x8v*)(kb_lo + ko + 32);
        const bf16x8v k2h = *(const bf16x8v*)(kb_hi + ko + 32);
        const bf16x8v k3l = *(const bf16x8v*)(kb_lo + ko + 48);
        const bf16x8v k3h = *(const bf16x8v*)(kb_hi + ko + 48);

        f32x16 st0 = {}, st1 = {};
        st0 = __builtin_amdgcn_mfma_f32_32x32x16_bf16(k0l, qf0, st0, 0, 0, 0);
        st1 = __builtin_amdgcn_mfma_f32_32x32x16_bf16(k0h, qf0, st1, 0, 0, 0);
        st0 = __builtin_amdgcn_mfma_f32_32x32x16_bf16(k1l, qf1, st0, 0, 0, 0);
        st1 = __builtin_amdgcn_mfma_f32_32x32x16_bf16(k1h, qf1, st1, 0, 0, 0);
        st0 = __builtin_amdgcn_mfma_f32_32x32x16_bf16(k2l, qf2, st0, 0, 0, 0);
        st1 = __builtin_amdgcn_mfma_f32_32x32x16_bf16(k2h, qf2, st1, 0, 0, 0);
        st0 = __builtin_amdgcn_mfma_f32_32x32x16_bf16(k3l, qf3, st0, 0, 0, 0);
        st1 = __builtin_amdgcn_mfma_f32_32x32x16_bf16(k3h, qf3, st1, 0, 0, 0);

        if (T == kd_w) {  // causal mask (diagonal tile)
            const int kb0 = T * 64, qg = q0 + c;
#pragma unroll
            for (int r = 0; r < 16; ++r) {
                const int krow = (r & 3) + 8 * (r >> 2) + 4 * h;
                if (kb0 + krow > qg)      st0[r] = -3e38f;
                if (kb0 + 32 + krow > qg) st1[r] = -3e38f;
            }
        }

        // online softmax (log2 domain), T13 defer-max
        {
            const float p0 = MX3(st0[0], st0[1], st0[2]);
            const float p1 = MX3(st0[3], st0[4], st0[5]);
            const float p2 = MX3(st0[6], st0[7], st0[8]);
            const float p3 = MX3(st0[9], st0[10], st0[11]);
            const float p4 = MX3(st0[12], st0[13], st0[14]);
            const float p5 = MX3(st0[15], st1[0], st1[1]);
            const float p6 = MX3(st1[2], st1[3], st1[4]);
            const float p7 = MX3(st1[5], st1[6], st1[7]);
            const float p8 = MX3(st1[8], st1[9], st1[10]);
            const float p9 = MX3(st1[11], st1[12], st1[13]);
            const float pa = fmaxf(st1[14], st1[15]);
            const float t0_ = MX3(p0, p1, p2);
            const float t1_ = MX3(p3, p4, p5);
            const float t2_ = MX3(p6, p7, p8);
            float mt = MX3(MX3(t0_, t1_, t2_), p9, pa);
            mt = fmaxf(mt, xhalf(mt, h));
            if (!__all(mt - mrow <= 8.0f)) {
                const float mn = fmaxf(mrow, mt);
                const float al = __builtin_amdgcn_exp2f(mrow - mn);
                mrow = mn;
                lrow *= al;
#pragma unroll
                for (int r = 0; r < 16; ++r) { oa0[r] *= al; oa1[r] *= al; }
            }
        }
#pragma unroll
        for (int r = 0; r < 16; ++r) st0[r] = __builtin_amdgcn_exp2f(st0[r] - mrow);
#pragma unroll
        for (int r = 0; r < 16; ++r) st1[r] = __builtin_amdgcn_exp2f(st1[r] - mrow);
        {
            const float s00 = (st0[0] + st0[1]) + (st0[2] + st0[3]);
            const float s01 = (st0[4] + st0[5]) + (st0[6] + st0[7]);
            const float s02 = (st0[8] + st0[9]) + (st0[10] + st0[11]);
            const float s03 = (st0[12] + st0[13]) + (st0[14] + st0[15]);
            const float s10 = (st1[0] + st1[1]) + (st1[2] + st1[3]);
            const float s11 = (st1[4] + st1[5]) + (st1[6] + st1[7]);
            const float s12 = (st1[8] + st1[9]) + (st1[10] + st1[11]);
            const float s13 = (st1[12] + st1[13]) + (st1[14] + st1[15]);
            float rs = ((s00 + s01) + (s02 + s03)) + ((s10 + s11) + (s12 + s13));
            rs += xhalf(rs, h);
            lrow += rs;
        }

        // V fragments (issued post-softmax: latency hides under pack + TLP)
        const bf16x8v v0l = *(const bf16x8v*)(vb_lo + vo);
        const bf16x8v v0h = *(const bf16x8v*)(vb_hi + vo);
        const bf16x8v v1l = *(const bf16x8v*)(vb_lo + vo + 16);
        const bf16x8v v1h = *(const bf16x8v*)(vb_hi + vo + 16);
        const bf16x8v v2l = *(const bf16x8v*)(vb_lo + vo + 32);
        const bf16x8v v2h = *(const bf16x8v*)(vb_hi + vo + 32);
        const bf16x8v v3l = *(const bf16x8v*)(vb_lo + vo + 48);
        const bf16x8v v3h = *(const bf16x8v*)(vb_hi + vo + 48);

        PV_STEP(st0, 0, v0l, v0h)
        PV_STEP(st0, 1, v1l, v1h)
        PV_STEP(st1, 0, v2l, v2h)
        PV_STEP(st1, 1, v3l, v3h)
    }
#undef PV_STEP
#undef MX3

    // ---- merge wave-pair partials (flash combine) through LDS ----
    __syncthreads();
    float* mbuf = smem_f + qs * 2176;   // 34 floats x 64 lanes per pair
    if (half) {
#pragma unroll
        for (int r = 0; r < 16; ++r) {
            mbuf[64 * r + lane]        = oa0[r];
            mbuf[64 * (16 + r) + lane] = oa1[r];
        }
        mbuf[64 * 32 + lane] = mrow;
        mbuf[64 * 33 + lane] = lrow;
    }
    __syncthreads();
    if (!half) {
        const float m1 = mbuf[64 * 32 + lane];
        const float l1 = mbuf[64 * 33 + lane];
        const float mm = fmaxf(mrow, m1);
        const float a0 = __builtin_amdgcn_exp2f(mrow - mm);
        const float a1 = __builtin_amdgcn_exp2f(m1 - mm);
        lrow = lrow * a0 + l1 * a1;
#pragma unroll
        for (int r = 0; r < 16; ++r) {
            oa0[r] = oa0[r] * a0 + mbuf[64 * r + lane] * a1;
            oa1[r] = oa1[r] * a0 + mbuf[64 * (16 + r) + lane] * a1;
        }
    }
    __syncthreads();   // all merge reads done before transpose overwrites

    if (!half) {       // even waves: transpose + coalesced store of 32 q-rows
        const float inv = 1.f / lrow;
        __bf16* ol = (__bf16*)smem_f + qs * 2304;
#pragma unroll
        for (int r = 0; r < 16; ++r) {
            const int crow = (r & 3) + 8 * (r >> 2) + 4 * h;
            ol[c * 72 + crow]      = (__bf16)(oa0[r] * inv);
            ol[c * 72 + 32 + crow] = (__bf16)(oa1[r] * inv);
        }
        const int bI = bh >> 4, hh = bh & 15;
        const int qr0 = lane >> 3, cb8 = lane & 7;
#pragma unroll
        for (int mm2 = 0; mm2 < 4; ++mm2) {
            const int qr = qr0 + 8 * mm2;
            const bf16x8v vv = *(const bf16x8v*)&ol[qr * 72 + cb8 * 8];
            *(bf16x8v*)(o + ((size_t)(bI * NS + q0 + qr)) * ND + hh * NDK + cb8 * 8) = vv;
        }
    }
}

// ---------------- output projection (named-reg m97 structure, 3 blocks/CU) ----------------
__global__ void __launch_bounds__(256, 3)
oproj_kernel(const __bf16* __restrict__ a, const __bf16* __restrict__ wob,
             float* __restrict__ out)
{
    __shared__ __align__(16) __bf16 a_lds[128 * 32];
    __shared__ __align__(16) __bf16 b_lds[128 * 32];

    const int t = threadIdx.x, w = t >> 6, lane = t & 63;
    const int g = lane >> 4, c = lane & 15;
    const int bm = blockIdx.x, bn = blockIdx.y;
    const int wm = w >> 1, wn = w & 1;

    f32x4 acc00 = {}, acc01 = {}, acc02 = {}, acc03 = {};
    f32x4 acc10 = {}, acc11 = {}, acc12 = {}, acc13 = {};
    f32x4 acc20 = {}, acc21 = {}, acc22 = {}, acc23 = {};
    f32x4 acc30 = {}, acc31 = {}, acc32 = {}, acc33 = {};

    const int sl = (g ^ (c & 3)) * 8;
    const __bf16* arow = &a_lds[(wm * 64 + c) * 32 + sl];
    const __bf16* brow = &b_lds[(wn * 64 + c) * 32 + sl];

    for (int kt = 0; kt < 32; ++kt) {
        __syncthreads();
#pragma unroll
        for (int j = 0; j < 2; ++j) {
            const int G = (w * 2 + j) * 64 + lane;
            const int r = G >> 2, cb = (G & 3) ^ (r & 3);
            gload16(a   + (size_t)(bm * 128 + r) * ND + kt * 32 + cb * 8,
                    &a_lds[(w * 2 + j) * 512]);
            gload16(wob + (size_t)(bn * 128 + r) * ND + kt * 32 + cb * 8,
                    &b_lds[(w * 2 + j) * 512]);
        }
        __syncthreads();
        const bf16x8v af0 = *(const bf16x8v*)(arow);
        const bf16x8v af1 = *(const bf16x8v*)(arow + 512);
        const bf16x8v af2 = *(const bf16x8v*)(arow + 1024);
        const bf16x8v af3 = *(const bf16x8v*)(arow + 1536);
        const bf16x8v bf0 = *(const bf16x8v*)(brow);
        const bf16x8v bf1 = *(const bf16x8v*)(brow + 512);
        const bf16x8v bf2 = *(const bf16x8v*)(brow + 1024);
        const bf16x8v bf3 = *(const bf16x8v*)(brow + 1536);
#define MM(FM, FN) acc##FM##FN = __builtin_amdgcn_mfma_f32_16x16x32_bf16( \
        af##FM, bf##FN, acc##FM##FN, 0, 0, 0);
        MM(0,0) MM(0,1) MM(0,2) MM(0,3)
        MM(1,0) MM(1,1) MM(1,2) MM(1,3)
        MM(2,0) MM(2,1) MM(2,2) MM(2,3)
        MM(3,0) MM(3,1) MM(3,2) MM(3,3)
#undef MM
    }

#define EPO(FM, FN, A)                                                     \
    {                                                                      \
        const int m0 = bm * 128 + wm * 64 + (FM) * 16 + g * 4;             \
        const int n = bn * 128 + wn * 64 + (FN) * 16 + c;                  \
        out[(size_t)(m0 + 0) * ND + n] = A[0];                             \
        out[(size_t)(m0 + 1) * ND + n] = A[1];                             \
        out[(size_t)(m0 + 2) * ND + n] = A[2];                             \
        out[(size_t)(m0 + 3) * ND + n] = A[3];                             \
    }
    EPO(0,0,acc00) EPO(0,1,acc01) EPO(0,2,acc02) EPO(0,3,acc03)
    EPO(1,0,acc10) EPO(1,1,acc11) EPO(1,2,acc12) EPO(1,3,acc13)
    EPO(2,0,acc20) EPO(2,1,acc21) EPO(2,2,acc22) EPO(2,3,acc23)
    EPO(3,0,acc30) EPO(3,1,acc31) EPO(3,2,acc32) EPO(3,3,acc33)
#undef EPO
}

extern "C" void kernel_launch(void* const* d_in, const int* in_sizes, int n_in,
                              void* d_out, int out_size, void* d_ws, size_t ws_size,
                              hipStream_t stream)
{
    const float* x  = (const float*)d_in[0];
    const float* wq = (const float*)d_in[1];
    const float* wk = (const float*)d_in[2];
    const float* wv = (const float*)d_in[3];
    const float* wo = (const float*)d_in[4];
    const int*  pos = (const int*)d_in[5];
    float* out = (float*)d_out;
    (void)in_sizes; (void)n_in; (void)out_size; (void)ws_size;

    float* cos_t = (float*)d_ws;
    float* sin_t = cos_t + NS * 32;

    const size_t xel = (size_t)NB * NS * ND;   // 4.2M
    const size_t wel = (size_t)ND * ND;        // 1.05M
    __bf16* xb  = (__bf16*)(sin_t + NS * 32);
    __bf16* wqb = xb  + xel;
    __bf16* wkb = wqb + wel;
    __bf16* wvb = wkb + wel;
    __bf16* wob = wvb + wel;
    __bf16* qw  = wob + wel;
    __bf16* kw  = qw  + xel;
    __bf16* vtw = kw  + xel;
    __bf16* aw  = vtw + xel;

    prep_kernel<<<4352, 256, 0, stream>>>(x, wq, wk, wv, wo, pos,
                                          xb, wqb, wkb, wvb, wob, cos_t, sin_t);

    dim3 qg(32, 24);  // 32 m-tiles x (8 n-tiles x {Q,K,V})
    qkv_kernel<<<qg, 256, 0, stream>>>(xb, wqb, wkb, wvb, cos_t, sin_t, qw, kw, vtw);

    attn_kernel<<<1024, 256, 0, stream>>>(qw, kw, vtw, aw);

    dim3 og(32, 8);
    oproj_kernel<<<og, 256, 0, stream>>>(aw, wob, out);
}

// Round 15
// 98.444 us; speedup vs baseline: 1.3576x; 1.3576x over previous
//
#include <hip/hip_runtime.h>
#include <hip/hip_bf16.h>
#include <stdint.h>

typedef __attribute__((ext_vector_type(4))) float f32x4;
typedef __attribute__((ext_vector_type(16))) float f32x16;
typedef __bf16 bf16x8v __attribute__((ext_vector_type(8)));
typedef __attribute__((ext_vector_type(4))) unsigned int u32x4;
typedef __attribute__((ext_vector_type(2))) unsigned int u32x2;

constexpr int NB = 2;
constexpr int NS = 2048;
constexpr int ND = 1024;
constexpr int NH = 16;
constexpr int NDK = 64;

__device__ __forceinline__ void gload16(const void* g, void* l) {
    __builtin_amdgcn_global_load_lds(
        (const __attribute__((address_space(1))) unsigned int*)g,
        (__attribute__((address_space(3))) unsigned int*)l, 16, 0, 0);
}

__device__ __forceinline__ unsigned pack_bf16x2(float lo, float hi) {
    unsigned short a = __builtin_bit_cast(unsigned short, (__bf16)lo);
    unsigned short b = __builtin_bit_cast(unsigned short, (__bf16)hi);
    return (unsigned)a | ((unsigned)b << 16);
}

// cross-half exchange: returns partner half's value of v (lane c <-> lane c+32)
__device__ __forceinline__ float xhalf(float v, int h) {
    const unsigned u = __builtin_bit_cast(unsigned, v);
    const u32x2 r = __builtin_amdgcn_permlane32_swap(u, u, false, false);
    return __builtin_bit_cast(float, h ? r[0] : r[1]);
}

// ---------------- prep: fp32->bf16 convert (x + 4 weights) + RoPE tables ----------------
__global__ void __launch_bounds__(256)
prep_kernel(const float* __restrict__ x, const float* __restrict__ wq,
            const float* __restrict__ wk, const float* __restrict__ wv,
            const float* __restrict__ wo, const int* __restrict__ pos,
            __bf16* __restrict__ xb, __bf16* __restrict__ wqb,
            __bf16* __restrict__ wkb, __bf16* __restrict__ wvb,
            __bf16* __restrict__ wob,
            float* __restrict__ cos_t, float* __restrict__ sin_t)
{
    int b = blockIdx.x;
    if (b >= 4096) {  // RoPE cos/sin tables [s][p], p=0..31
        const int idx = (b - 4096) * 256 + threadIdx.x;  // 65536 = 2048*32
        const int s = idx >> 5, p = idx & 31;
        const float freq = __expf((float)p * (-0.28782313662425572f));  // ln(1e4)/32
        const float ang = (float)pos[s] * freq;
        float sn, cs;
        sincosf(ang, &sn, &cs);
        cos_t[idx] = cs;
        sin_t[idx] = sn;
        return;
    }
    const float* s; __bf16* d;
    if (b < 2048)      { s = x;  d = xb;            }
    else if (b < 2560) { s = wq; d = wqb; b -= 2048; }
    else if (b < 3072) { s = wk; d = wkb; b -= 2560; }
    else if (b < 3584) { s = wv; d = wvb; b -= 3072; }
    else               { s = wo; d = wob; b -= 3584; }
    const size_t i = ((size_t)b * 256 + threadIdx.x) * 8;
    const f32x4 v0 = *(const f32x4*)(s + i);
    const f32x4 v1 = *(const f32x4*)(s + i + 4);
    bf16x8v o;
#pragma unroll
    for (int j = 0; j < 4; ++j) { o[j] = (__bf16)v0[j]; o[4+j] = (__bf16)v1[j]; }
    *(bf16x8v*)(d + i) = o;
}

// ---- shared GEMM epilogue piece (RoPE-from-table or V^T store), no calls ----
__device__ __forceinline__ void epi_one(
    f32x4 a, int fm, int fn, int bm, int wm, int g, int c, int mode, int h_out,
    const float* __restrict__ cos_t, const float* __restrict__ sin_t,
    __bf16* __restrict__ qw, __bf16* __restrict__ kw, __bf16* __restrict__ vtw)
{
    const int m0 = bm * 128 + wm * 64 + fm * 16 + g * 4;
    const int bI = m0 >> 11, s0 = m0 & (NS - 1);
    const int d = fn * 16 + c;
    float v0 = a[0], v1 = a[1], v2 = a[2], v3 = a[3];
    if (mode < 2) {
        const int p = d >> 1;
        const bool odd = (d & 1);
        const float sc = (mode == 0) ? 0.18033688011112042f : 1.0f;  // 0.125*log2(e)
#define ROPE1(V, I)                                                        \
        {                                                                  \
            const float cs = cos_t[(s0 + (I)) * 32 + p];                   \
            const float sn = sin_t[(s0 + (I)) * 32 + p];                   \
            const float oth = __shfl_xor(V, 1, 64);                       \
            V = (odd ? (oth * sn + V * cs) : (V * cs - oth * sn)) * sc;    \
        }
        ROPE1(v0, 0) ROPE1(v1, 1) ROPE1(v2, 2) ROPE1(v3, 3)
#undef ROPE1
        __bf16* dq = (mode == 0) ? qw : kw;
        __bf16* b = dq + (((size_t)bI * NH + h_out) * NS + s0) * NDK + d;
        b[0] = (__bf16)v0; b[NDK] = (__bf16)v1;
        b[2 * NDK] = (__bf16)v2; b[3 * NDK] = (__bf16)v3;
    } else {
        ushort4 pk;
        pk.x = __builtin_bit_cast(unsigned short, (__bf16)v0);
        pk.y = __builtin_bit_cast(unsigned short, (__bf16)v1);
        pk.z = __builtin_bit_cast(unsigned short, (__bf16)v2);
        pk.w = __builtin_bit_cast(unsigned short, (__bf16)v3);
        *(ushort4*)&vtw[(((size_t)bI * NH + h_out) * NDK + d) * NS + s0] = pk;
    }
}

// ---------------- fused QKV projection GEMM (BK=64: half the barriers) ----------------
// 128x128 tile, BK=64 (32KB LDS, still 3 blocks/CU; m132's regression was
// BK=128's 64KB). 16 K-iters x {8 gload16, 2 barriers, 16 ds_read, 32 MFMA}.
__global__ void __launch_bounds__(256, 3)
qkv_kernel(const __bf16* __restrict__ xb,
           const __bf16* __restrict__ wqb, const __bf16* __restrict__ wkb,
           const __bf16* __restrict__ wvb,
           const float* __restrict__ cos_t, const float* __restrict__ sin_t,
           __bf16* __restrict__ qw, __bf16* __restrict__ kw,
           __bf16* __restrict__ vtw)
{
    __shared__ __align__(16) __bf16 a_lds[128 * 64];
    __shared__ __align__(16) __bf16 b_lds[128 * 64];

    const int t = threadIdx.x, w = t >> 6, lane = t & 63;
    const int g = lane >> 4, c = lane & 15;
    const int bm = blockIdx.x, bn = blockIdx.y;
    const int mode = bn >> 3, nblk = bn & 7;
    const __bf16* wsel = (mode == 0) ? wqb : (mode == 1) ? wkb : wvb;
    const int wm = w >> 1, wn = w & 1;

    f32x4 acc00 = {}, acc01 = {}, acc02 = {}, acc03 = {};
    f32x4 acc10 = {}, acc11 = {}, acc12 = {}, acc13 = {};
    f32x4 acc20 = {}, acc21 = {}, acc22 = {}, acc23 = {};
    f32x4 acc30 = {}, acc31 = {}, acc32 = {}, acc33 = {};

    // staging: G = j*256+t -> row r=G>>3 (0..127), slot cb=G&7; source col
    // pre-swizzled by r&7 ( = t>>3 & 7, j-invariant). Dest chunk lane-linear.
    const int csw = ((t & 7) ^ ((t >> 3) & 7)) * 8;
    // fragment reads: row ra = wm*64+f*16+c (ra&7 = c&7); slot (kk*4+g)^(c&7)
    const int sx = c & 7;
    const int sl0 = (g ^ sx) * 8;          // kk=0
    const int sl1 = ((4 + g) ^ sx) * 8;    // kk=1
    const __bf16* arow = &a_lds[(wm * 64 + c) * 64];
    const __bf16* brow = &b_lds[(wn * 64 + c) * 64];

    for (int kt = 0; kt < 16; ++kt) {
        __syncthreads();
#pragma unroll
        for (int j = 0; j < 4; ++j) {
            const int r = (j * 256 + t) >> 3;
            gload16(xb   + (size_t)(bm   * 128 + r) * ND + kt * 64 + csw,
                    &a_lds[j * 2048 + w * 512]);
            gload16(wsel + (size_t)(nblk * 128 + r) * ND + kt * 64 + csw,
                    &b_lds[j * 2048 + w * 512]);
        }
        __syncthreads();
#define MM(FM, FN, AF, BF) acc##FM##FN = __builtin_amdgcn_mfma_f32_16x16x32_bf16( \
        AF, BF, acc##FM##FN, 0, 0, 0);
#define KKSTEP(SL)                                                            \
        {                                                                     \
            const bf16x8v af0 = *(const bf16x8v*)(arow + (SL));               \
            const bf16x8v af1 = *(const bf16x8v*)(arow + 1024 + (SL));        \
            const bf16x8v af2 = *(const bf16x8v*)(arow + 2048 + (SL));        \
            const bf16x8v af3 = *(const bf16x8v*)(arow + 3072 + (SL));        \
            const bf16x8v bf0 = *(const bf16x8v*)(brow + (SL));               \
            const bf16x8v bf1 = *(const bf16x8v*)(brow + 1024 + (SL));        \
            const bf16x8v bf2 = *(const bf16x8v*)(brow + 2048 + (SL));        \
            const bf16x8v bf3 = *(const bf16x8v*)(brow + 3072 + (SL));        \
            MM(0,0,af0,bf0) MM(0,1,af0,bf1) MM(0,2,af0,bf2) MM(0,3,af0,bf3)   \
            MM(1,0,af1,bf0) MM(1,1,af1,bf1) MM(1,2,af1,bf2) MM(1,3,af1,bf3)   \
            MM(2,0,af2,bf0) MM(2,1,af2,bf1) MM(2,2,af2,bf2) MM(2,3,af2,bf3)   \
            MM(3,0,af3,bf0) MM(3,1,af3,bf1) MM(3,2,af3,bf2) MM(3,3,af3,bf3)   \
        }
        KKSTEP(sl0)
        KKSTEP(sl1)
#undef KKSTEP
#undef MM
    }

    const int h_out = nblk * 2 + wn;
#define EP(FM, FN) epi_one(acc##FM##FN, FM, FN, bm, wm, g, c, mode, h_out, \
                           cos_t, sin_t, qw, kw, vtw);
    EP(0,0) EP(0,1) EP(0,2) EP(0,3)
    EP(1,0) EP(1,1) EP(1,2) EP(1,3)
    EP(2,0) EP(2,1) EP(2,2) EP(2,3)
    EP(3,0) EP(3,1) EP(3,2) EP(3,3)
#undef EP
}

// ---------------- flash attention v11 (round-13 verbatim): KV-split wave pairs ----------------
// v12 (no-LDS direct-global fragments) regressed 2x: per-lane stride-128B
// fragment loads touch 32 cache lines/instr (8x L1 transactions) + serial
// latency. LDS staging via gload_lds IS the right structure for MFMA-layout
// reads. This is the round-13 kernel (attn ~36 us) unchanged.
__global__ void __launch_bounds__(512)
__attribute__((amdgpu_waves_per_eu(4, 4)))
attn_kernel(const __bf16* __restrict__ q, const __bf16* __restrict__ k,
            const __bf16* __restrict__ vt, __bf16* __restrict__ o)
{
    // K: half0 bufs @ {0,4160}, half1 @ {8320,12480}; V: same + 16640. 66.56 KB.
    __shared__ __align__(16) __bf16 smem[33280];

    const int t = threadIdx.x, w = t >> 6, lane = t & 63;
    const int c = lane & 31, h = lane >> 5;
    const int qs = w >> 1, half = w & 1;
    const int bid = blockIdx.x;
    const int idx = bid >> 5;                          // 0..15
    const int qt16 = (idx < 8) ? (15 - idx) : (idx - 8);  // pairs sum to 15
    const int bh = bid & 31;                           // B*H = 32 exactly
    const size_t base = (size_t)bh * NS * NDK;
    const int q0 = qt16 * 128 + qs * 32;
    const int kd_w = 2 * qt16 + (qs >> 1);             // diagonal tile index
    const int NH0 = qt16 + 1;                          // iterations per wave
    const int Tof = half * NH0;                        // my K-tile offset

    // Q B-frags: lane (c,h) holds Q[q0+c][16ds+8h+j]
    bf16x8v qf0, qf1, qf2, qf3;
    {
        const __bf16* qp = q + base + (size_t)(q0 + c) * NDK + h * 8;
        qf0 = *(const bf16x8v*)(qp);
        qf1 = *(const bf16x8v*)(qp + 16);
        qf2 = *(const bf16x8v*)(qp + 32);
        qf3 = *(const bf16x8v*)(qp + 48);
    }

    // staging: thread t -> row r0 = t>>3 (0..63), slot cb0 = t&7; wave w's 64
    // lanes write one contiguous 1KB chunk at w*520 elems (lane-linear dest).
    // Source column pre-swizzled: LDS slot s of row r holds global col s^(r&7).
    const int r0 = t >> 3, cb0 = t & 7;
    const int csw = (cb0 ^ (r0 & 7)) * 8;
    const __bf16* ksrc = k  + base + (size_t)r0 * NDK + csw;
    const __bf16* vsrc = vt + base + (size_t)r0 * NS  + csw;

    // loop-invariant read addressing: row r at (r>>3)*520 + (r&7)*64; +2080 for r+32
    const int rbase = (c >> 3) * 520 + (c & 7) * 64;
    const int sl0 = ((0 + h) ^ (c & 7)) * 8;
    const int sl1 = ((2 + h) ^ (c & 7)) * 8;
    const int sl2 = ((4 + h) ^ (c & 7)) * 8;
    const int sl3 = ((6 + h) ^ (c & 7)) * 8;

// stage iteration I's tiles: tile I (half0 bufs) and tile NH0+I (half1 bufs)
#define STAGE(I) {                                                             \
        gload16(ksrc + (size_t)(I) * 4096,                                     \
                smem + ((I) & 1) * 4160 + w * 520);                            \
        gload16(ksrc + (size_t)((I) + NH0) * 4096,                             \
                smem + 8320 + ((I) & 1) * 4160 + w * 520);                     \
        gload16(vsrc + (I) * 64,                                               \
                smem + 16640 + ((I) & 1) * 4160 + w * 520);                    \
        gload16(vsrc + ((I) + NH0) * 64,                                       \
                smem + 16640 + 8320 + ((I) & 1) * 4160 + w * 520); }

    float mrow = -3e38f, lrow = 0.f;
    f32x16 oa0 = {}, oa1 = {};

// full per-tile compute on tile T from buffer parity I: QK^T, mask, softmax, PV
#define COMPUTE(T, I) {                                                       \
    const __bf16* kb = smem + half * 8320 + ((I) & 1) * 4160;                 \
    const __bf16* vb = kb + 16640;                                            \
    f32x16 st0 = {}, st1 = {};                                                \
    {                                                                         \
        const __bf16* klo = kb + rbase;                                      \
        const __bf16* khi = kb + rbase + 2080;                               \
        st0 = __builtin_amdgcn_mfma_f32_32x32x16_bf16(                        \
            *(const bf16x8v*)(klo + sl0), qf0, st0, 0, 0, 0);                 \
        st1 = __builtin_amdgcn_mfma_f32_32x32x16_bf16(                        \
            *(const bf16x8v*)(khi + sl0), qf0, st1, 0, 0, 0);                 \
        st0 = __builtin_amdgcn_mfma_f32_32x32x16_bf16(                        \
            *(const bf16x8v*)(klo + sl1), qf1, st0, 0, 0, 0);                 \
        st1 = __builtin_amdgcn_mfma_f32_32x32x16_bf16(                        \
            *(const bf16x8v*)(khi + sl1), qf1, st1, 0, 0, 0);                 \
        st0 = __builtin_amdgcn_mfma_f32_32x32x16_bf16(                        \
            *(const bf16x8v*)(klo + sl2), qf2, st0, 0, 0, 0);                 \
        st1 = __builtin_amdgcn_mfma_f32_32x32x16_bf16(                        \
            *(const bf16x8v*)(khi + sl2), qf2, st1, 0, 0, 0);                 \
        st0 = __builtin_amdgcn_mfma_f32_32x32x16_bf16(                        \
            *(const bf16x8v*)(klo + sl3), qf3, st0, 0, 0, 0);                 \
        st1 = __builtin_amdgcn_mfma_f32_32x32x16_bf16(                        \
            *(const bf16x8v*)(khi + sl3), qf3, st1, 0, 0, 0);                 \
    }                                                                         \
    if ((T) == kd_w) {                                                        \
        const int kb0 = (T) * 64, qg = q0 + c;                                \
        _Pragma("unroll")                                                     \
        for (int r = 0; r < 16; ++r) {                                        \
            const int krow = (r & 3) + 8 * (r >> 2) + 4 * h;                  \
            if (kb0 + krow > qg)      st0[r] = -3e38f;                        \
            if (kb0 + 32 + krow > qg) st1[r] = -3e38f;                        \
        }                                                                     \
    }                                                                         \
    {                                                                         \
        const float p0 = MX3(st0[0], st0[1], st0[2]);                         \
        const float p1 = MX3(st0[3], st0[4], st0[5]);                         \
        const float p2 = MX3(st0[6], st0[7], st0[8]);                         \
        const float p3 = MX3(st0[9], st0[10], st0[11]);                       \
        const float p4 = MX3(st0[12], st0[13], st0[14]);                      \
        const float p5 = MX3(st0[15], st1[0], st1[1]);                        \
        const float p6 = MX3(st1[2], st1[3], st1[4]);                         \
        const float p7 = MX3(st1[5], st1[6], st1[7]);                         \
        const float p8 = MX3(st1[8], st1[9], st1[10]);                        \
        const float p9 = MX3(st1[11], st1[12], st1[13]);                      \
        const float pa = fmaxf(st1[14], st1[15]);                             \
        const float t0_ = MX3(p0, p1, p2);                                    \
        const float t1_ = MX3(p3, p4, p5);                                    \
        const float t2_ = MX3(p6, p7, p8);                                    \
        float mt = MX3(MX3(t0_, t1_, t2_), p9, pa);                           \
        mt = fmaxf(mt, xhalf(mt, h));                                         \
        if (!__all(mt - mrow <= 8.0f)) {                                      \
            const float mn = fmaxf(mrow, mt);                                 \
            const float al = __builtin_amdgcn_exp2f(mrow - mn);               \
            mrow = mn;                                                        \
            lrow *= al;                                                       \
            _Pragma("unroll")                                                 \
            for (int r = 0; r < 16; ++r) { oa0[r] *= al; oa1[r] *= al; }      \
        }                                                                     \
    }                                                                         \
    _Pragma("unroll")                                                         \
    for (int r = 0; r < 16; ++r) st0[r] = __builtin_amdgcn_exp2f(st0[r] - mrow); \
    _Pragma("unroll")                                                         \
    for (int r = 0; r < 16; ++r) st1[r] = __builtin_amdgcn_exp2f(st1[r] - mrow); \
    {                                                                         \
        const float s00 = (st0[0] + st0[1]) + (st0[2] + st0[3]);              \
        const float s01 = (st0[4] + st0[5]) + (st0[6] + st0[7]);              \
        const float s02 = (st0[8] + st0[9]) + (st0[10] + st0[11]);            \
        const float s03 = (st0[12] + st0[13]) + (st0[14] + st0[15]);          \
        const float s10 = (st1[0] + st1[1]) + (st1[2] + st1[3]);              \
        const float s11 = (st1[4] + st1[5]) + (st1[6] + st1[7]);              \
        const float s12 = (st1[8] + st1[9]) + (st1[10] + st1[11]);            \
        const float s13 = (st1[12] + st1[13]) + (st1[14] + st1[15]);          \
        float rs = ((s00 + s01) + (s02 + s03)) + ((s10 + s11) + (s12 + s13)); \
        rs += xhalf(rs, h);                                                   \
        lrow += rs;                                                           \
    }                                                                         \
    PV_STEP(st0, 0, sl0)                                                      \
    PV_STEP(st0, 1, sl1)                                                      \
    PV_STEP(st1, 0, sl2)                                                      \
    PV_STEP(st1, 1, sl3)                                                      \
}

#define MX3(a, b, cc) fmaxf(fmaxf((a), (b)), (cc))
#define PV_STEP(ST, T, SLT)  {                                                \
    const unsigned w0_ = pack_bf16x2(ST[8*(T)+0], ST[8*(T)+1]);               \
    const unsigned w1_ = pack_bf16x2(ST[8*(T)+2], ST[8*(T)+3]);               \
    const unsigned w2_ = pack_bf16x2(ST[8*(T)+4], ST[8*(T)+5]);               \
    const unsigned w3_ = pack_bf16x2(ST[8*(T)+6], ST[8*(T)+7]);               \
    const u32x2 r02 = __builtin_amdgcn_permlane32_swap(w0_, w2_, false, false); \
    const u32x2 r13 = __builtin_amdgcn_permlane32_swap(w1_, w3_, false, false); \
    const u32x4 pu = { r02[0], r13[0], r02[1], r13[1] };                      \
    const bf16x8v pf = __builtin_bit_cast(bf16x8v, pu);                       \
    const bf16x8v v0_ = *(const bf16x8v*)(vb + rbase + (SLT));                \
    const bf16x8v v1_ = *(const bf16x8v*)(vb + rbase + 2080 + (SLT));         \
    oa0 = __builtin_amdgcn_mfma_f32_32x32x16_bf16(v0_, pf, oa0, 0, 0, 0);     \
    oa1 = __builtin_amdgcn_mfma_f32_32x32x16_bf16(v1_, pf, oa1, 0, 0, 0); }

    STAGE(0)
    __syncthreads();   // drain prologue loads

    for (int i = 0; ; ++i) {
        if (i + 1 < NH0) STAGE(i + 1)   // async into other buffers
        const int T = Tof + i;
        if (T <= kd_w) COMPUTE(T, i)    // wave-uniform skip (no barrier inside)
        if (i + 1 == NH0) break;
        __syncthreads();   // drains STAGE(i+1); fences buffer reuse
    }
#undef COMPUTE
#undef PV_STEP
#undef MX3
#undef STAGE

    // ---- merge wave-pair partials (flash combine), KV buffers now dead ----
    __syncthreads();
    float* mbuf = (float*)smem + qs * 2176;   // 34 floats x 64 lanes per pair
    if (half) {
#pragma unroll
        for (int r = 0; r < 16; ++r) {
            mbuf[64 * r + lane]        = oa0[r];
            mbuf[64 * (16 + r) + lane] = oa1[r];
        }
        mbuf[64 * 32 + lane] = mrow;
        mbuf[64 * 33 + lane] = lrow;
    }
    __syncthreads();
    if (!half) {
        const float m1 = mbuf[64 * 32 + lane];
        const float l1 = mbuf[64 * 33 + lane];
        const float mm = fmaxf(mrow, m1);
        const float a0 = __builtin_amdgcn_exp2f(mrow - mm);
        const float a1 = __builtin_amdgcn_exp2f(m1 - mm);
        lrow = lrow * a0 + l1 * a1;
#pragma unroll
        for (int r = 0; r < 16; ++r) {
            oa0[r] = oa0[r] * a0 + mbuf[64 * r + lane] * a1;
            oa1[r] = oa1[r] * a0 + mbuf[64 * (16 + r) + lane] * a1;
        }
    }
    __syncthreads();   // all merge reads done before transpose overwrites

    if (!half) {       // even waves: transpose + coalesced store of 32 q-rows
        const float inv = 1.f / lrow;
        __bf16* ol = smem + qs * 2304;
#pragma unroll
        for (int r = 0; r < 16; ++r) {
            const int crow = (r & 3) + 8 * (r >> 2) + 4 * h;
            ol[c * 72 + crow]      = (__bf16)(oa0[r] * inv);
            ol[c * 72 + 32 + crow] = (__bf16)(oa1[r] * inv);
        }
        const int bI = bh >> 4, hh = bh & 15;
        const int qr0 = lane >> 3, cb8 = lane & 7;
#pragma unroll
        for (int mm2 = 0; mm2 < 4; ++mm2) {
            const int qr = qr0 + 8 * mm2;
            const bf16x8v vv = *(const bf16x8v*)&ol[qr * 72 + cb8 * 8];
            *(bf16x8v*)(o + ((size_t)(bI * NS + q0 + qr)) * ND + hh * NDK + cb8 * 8) = vv;
        }
    }
}

// ---------------- output projection (BK=64, named regs, 3 blocks/CU) ----------------
__global__ void __launch_bounds__(256, 3)
oproj_kernel(const __bf16* __restrict__ a, const __bf16* __restrict__ wob,
             float* __restrict__ out)
{
    __shared__ __align__(16) __bf16 a_lds[128 * 64];
    __shared__ __align__(16) __bf16 b_lds[128 * 64];

    const int t = threadIdx.x, w = t >> 6, lane = t & 63;
    const int g = lane >> 4, c = lane & 15;
    const int bm = blockIdx.x, bn = blockIdx.y;
    const int wm = w >> 1, wn = w & 1;

    f32x4 acc00 = {}, acc01 = {}, acc02 = {}, acc03 = {};
    f32x4 acc10 = {}, acc11 = {}, acc12 = {}, acc13 = {};
    f32x4 acc20 = {}, acc21 = {}, acc22 = {}, acc23 = {};
    f32x4 acc30 = {}, acc31 = {}, acc32 = {}, acc33 = {};

    const int csw = ((t & 7) ^ ((t >> 3) & 7)) * 8;
    const int sx = c & 7;
    const int sl0 = (g ^ sx) * 8;
    const int sl1 = ((4 + g) ^ sx) * 8;
    const __bf16* arow = &a_lds[(wm * 64 + c) * 64];
    const __bf16* brow = &b_lds[(wn * 64 + c) * 64];

    for (int kt = 0; kt < 16; ++kt) {
        __syncthreads();
#pragma unroll
        for (int j = 0; j < 4; ++j) {
            const int r = (j * 256 + t) >> 3;
            gload16(a   + (size_t)(bm * 128 + r) * ND + kt * 64 + csw,
                    &a_lds[j * 2048 + w * 512]);
            gload16(wob + (size_t)(bn * 128 + r) * ND + kt * 64 + csw,
                    &b_lds[j * 2048 + w * 512]);
        }
        __syncthreads();
#define MM(FM, FN, AF, BF) acc##FM##FN = __builtin_amdgcn_mfma_f32_16x16x32_bf16( \
        AF, BF, acc##FM##FN, 0, 0, 0);
#define KKSTEP(SL)                                                            \
        {                                                                     \
            const bf16x8v af0 = *(const bf16x8v*)(arow + (SL));               \
            const bf16x8v af1 = *(const bf16x8v*)(arow + 1024 + (SL));        \
            const bf16x8v af2 = *(const bf16x8v*)(arow + 2048 + (SL));        \
            const bf16x8v af3 = *(const bf16x8v*)(arow + 3072 + (SL));        \
            const bf16x8v bf0 = *(const bf16x8v*)(brow + (SL));               \
            const bf16x8v bf1 = *(const bf16x8v*)(brow + 1024 + (SL));        \
            const bf16x8v bf2 = *(const bf16x8v*)(brow + 2048 + (SL));        \
            const bf16x8v bf3 = *(const bf16x8v*)(brow + 3072 + (SL));        \
            MM(0,0,af0,bf0) MM(0,1,af0,bf1) MM(0,2,af0,bf2) MM(0,3,af0,bf3)   \
            MM(1,0,af1,bf0) MM(1,1,af1,bf1) MM(1,2,af1,bf2) MM(1,3,af1,bf3)   \
            MM(2,0,af2,bf0) MM(2,1,af2,bf1) MM(2,2,af2,bf2) MM(2,3,af2,bf3)   \
            MM(3,0,af3,bf0) MM(3,1,af3,bf1) MM(3,2,af3,bf2) MM(3,3,af3,bf3)   \
        }
        KKSTEP(sl0)
        KKSTEP(sl1)
#undef KKSTEP
#undef MM
    }

#define EPO(FM, FN, A)                                                     \
    {                                                                      \
        const int m0 = bm * 128 + wm * 64 + (FM) * 16 + g * 4;             \
        const int n = bn * 128 + wn * 64 + (FN) * 16 + c;                  \
        out[(size_t)(m0 + 0) * ND + n] = A[0];                             \
        out[(size_t)(m0 + 1) * ND + n] = A[1];                             \
        out[(size_t)(m0 + 2) * ND + n] = A[2];                             \
        out[(size_t)(m0 + 3) * ND + n] = A[3];                             \
    }
    EPO(0,0,acc00) EPO(0,1,acc01) EPO(0,2,acc02) EPO(0,3,acc03)
    EPO(1,0,acc10) EPO(1,1,acc11) EPO(1,2,acc12) EPO(1,3,acc13)
    EPO(2,0,acc20) EPO(2,1,acc21) EPO(2,2,acc22) EPO(2,3,acc23)
    EPO(3,0,acc30) EPO(3,1,acc31) EPO(3,2,acc32) EPO(3,3,acc33)
#undef EPO
}

extern "C" void kernel_launch(void* const* d_in, const int* in_sizes, int n_in,
                              void* d_out, int out_size, void* d_ws, size_t ws_size,
                              hipStream_t stream)
{
    const float* x  = (const float*)d_in[0];
    const float* wq = (const float*)d_in[1];
    const float* wk = (const float*)d_in[2];
    const float* wv = (const float*)d_in[3];
    const float* wo = (const float*)d_in[4];
    const int*  pos = (const int*)d_in[5];
    float* out = (float*)d_out;
    (void)in_sizes; (void)n_in; (void)out_size; (void)ws_size;

    float* cos_t = (float*)d_ws;
    float* sin_t = cos_t + NS * 32;

    const size_t xel = (size_t)NB * NS * ND;   // 4.2M
    const size_t wel = (size_t)ND * ND;        // 1.05M
    __bf16* xb  = (__bf16*)(sin_t + NS * 32);
    __bf16* wqb = xb  + xel;
    __bf16* wkb = wqb + wel;
    __bf16* wvb = wkb + wel;
    __bf16* wob = wvb + wel;
    __bf16* qw  = wob + wel;
    __bf16* kw  = qw  + xel;
    __bf16* vtw = kw  + xel;
    __bf16* aw  = vtw + xel;

    prep_kernel<<<4352, 256, 0, stream>>>(x, wq, wk, wv, wo, pos,
                                          xb, wqb, wkb, wvb, wob, cos_t, sin_t);

    dim3 qg(32, 24);  // 32 m-tiles x (8 n-tiles x {Q,K,V})
    qkv_kernel<<<qg, 256, 0, stream>>>(xb, wqb, wkb, wvb, cos_t, sin_t, qw, kw, vtw);

    attn_kernel<<<512, 512, 0, stream>>>(qw, kw, vtw, aw);

    dim3 og(32, 8);
    oproj_kernel<<<og, 256, 0, stream>>>(aw, wob, out);
}